// Round 9
// baseline (76.523 us; speedup 1.0000x reference)
//
#include <hip/hip_runtime.h>
#include <math.h>

#define NSAMP 4
#define NB 64
#define LVOL (64*64*64)
#define WPS 128                 // hist blocks per sample (512 total)
#define TILEB (68*64)           // 4352 B per k-block (68 rows x 32 k x 2B bf16)
#define KBLK 4                  // 4 k-blocks x 32 voxels = 128 voxels per iter
#define AREG (KBLK*TILEB)       // 17408 B per matrix region
#define LDSB (2*AREG)           // 34816 B total
// XOR-swizzle byte-addr bits 4..6 by row bits 1..3; applied identically on
// scatter-write, rezero, and frag-read. Bijective within each tile; all
// region bases (kb*TILEB, AREG) are multiples of 128 -> commute with SWZ.
#define SWZ(a,row) ((a) ^ ((((row)>>1)&7)<<4))

typedef __attribute__((ext_vector_type(8))) short bf16x8;
typedef __attribute__((ext_vector_type(4))) float f32x4;

__device__ __forceinline__ unsigned short f2bf(float x){  // RNE f32->bf16
  unsigned u = __float_as_uint(x);
  return (unsigned short)((u + 0x7FFFu + ((u >> 16) & 1u)) >> 16);
}

// ---- kernel 1: per-chunk min/max partials; zeroes hist + chain counters ----
__global__ __launch_bounds__(256) void k_minmax(const float* __restrict__ tgt,
                                                const float* __restrict__ src,
                                                float4* __restrict__ mmp,
                                                float* __restrict__ hist,
                                                int* __restrict__ cnt){
  if (blockIdx.x == 0 && threadIdx.x < 8) cnt[threadIdx.x] = 0;
  if (blockIdx.x < 64) hist[blockIdx.x * 256 + threadIdx.x] = 0.0f;  // 64KB
  const int n = blockIdx.x >> 7, chunk = blockIdx.x & 127;  // 128 chunks/sample
  const float4* t4 = (const float4*)(tgt + (size_t)n * LVOL) + (size_t)chunk * 256;
  const float4* s4 = (const float4*)(src + (size_t)n * LVOL) + (size_t)chunk * 256;
  float4 a = t4[threadIdx.x];
  float4 b = s4[threadIdx.x];
  float tmn = fminf(fminf(a.x, a.y), fminf(a.z, a.w));
  float tmx = fmaxf(fmaxf(a.x, a.y), fmaxf(a.z, a.w));
  float smn = fminf(fminf(b.x, b.y), fminf(b.z, b.w));
  float smx = fmaxf(fmaxf(b.x, b.y), fmaxf(b.z, b.w));
  for (int off = 32; off; off >>= 1){
    tmn = fminf(tmn, __shfl_down(tmn, off));
    tmx = fmaxf(tmx, __shfl_down(tmx, off));
    smn = fminf(smn, __shfl_down(smn, off));
    smx = fmaxf(smx, __shfl_down(smx, off));
  }
  __shared__ float red[4][4];
  const int wave = threadIdx.x >> 6, lane = threadIdx.x & 63;
  if (lane == 0){ red[wave][0]=tmn; red[wave][1]=tmx; red[wave][2]=smn; red[wave][3]=smx; }
  __syncthreads();
  if (threadIdx.x == 0){
    for (int w = 1; w < 4; ++w){
      tmn = fminf(tmn, red[w][0]); tmx = fmaxf(tmx, red[w][1]);
      smn = fminf(smn, red[w][2]); smx = fmaxf(smx, red[w][3]);
    }
    mmp[blockIdx.x] = make_float4(tmn, tmx, smn, smx);
  }
}

// ---- kernel 2: MFMA hist GEMM + atomic hist accumulate + chained tail ----
// GEMM core identical to round 8 (verified). Epilogue atomicAdds each wave's
// 32x32 quadrant into hist[n] (device-scope, coherence-point serviced), then
// chained counters: last block per sample computes entropies; last sample
// writes the output. No partials buffer at all.
__global__ __launch_bounds__(256, 4) void k_hist(const float* __restrict__ tgt,
                                                 const float* __restrict__ src,
                                                 const float4* __restrict__ mmp,
                                                 float* __restrict__ hist,
                                                 float* __restrict__ ratio,
                                                 int* __restrict__ cnt,
                                                 float* __restrict__ out){
  __shared__ __align__(16) char lds[LDSB];
  __shared__ int fl;
  __shared__ float rowsum[NB], colsum[NB], wr1[4], wr2[4], S_sh;
  const int tid = threadIdx.x, wv = tid >> 6, lane = tid & 63;
  const int n = blockIdx.x >> 7, wg = blockIdx.x & (WPS - 1);

  // per-wave redundant minmax reduce over this sample's 128 partials
  float4 v = mmp[n * 128 + lane];
  float4 v2 = mmp[n * 128 + 64 + lane];
  v.x = fminf(v.x, v2.x); v.y = fmaxf(v.y, v2.y);
  v.z = fminf(v.z, v2.z); v.w = fmaxf(v.w, v2.w);
  for (int off = 32; off; off >>= 1){
    v.x = fminf(v.x, __shfl_down(v.x, off));
    v.y = fmaxf(v.y, __shfl_down(v.y, off));
    v.z = fminf(v.z, __shfl_down(v.z, off));
    v.w = fmaxf(v.w, __shfl_down(v.w, off));
  }
  const float tmn = __shfl(v.x, 0), tmx = __shfl(v.y, 0);
  const float smn = __shfl(v.z, 0), smx = __shfl(v.w, 0);
  const float st = (float)NB / (tmx - tmn + 1e-12f);
  const float ss = (float)NB / (smx - smn + 1e-12f);

  // zero the tiles (2176 int4)
  {
    int4 zz = make_int4(0, 0, 0, 0);
    #pragma unroll
    for (int i = 0; i < 9; ++i){
      int idx = tid + i * 256;
      if (idx < LDSB / 16) ((int4*)lds)[idx] = zz;
    }
  }

  // scatter role (uniform per wave): half=0 -> T into A region, half=1 -> S
  const int half = tid >> 7, v7 = tid & 127;
  const int kb_w = v7 >> 5, k2 = v7 & 31;
  const int sbase = half * AREG + kb_w * TILEB + k2 * 2;
  const float mn = half ? smn : tmn;
  const float sc = half ? ss : st;
  const float* gsrc = half ? src : tgt;
  const size_t gbase = (size_t)n * LVOL + (size_t)wg * 2048 + v7;

  // fragment read offsets: wave's 32x32 quadrant
  const int r = lane & 15, g = lane >> 4;
  const int rb = 32 * (wv >> 1), cb = 32 * (wv & 1);
  int sa[2], sb[2];
  #pragma unroll
  for (int i = 0; i < 2; ++i){
    int ar = 1 + rb + 16 * i + r;
    sa[i] = SWZ(ar * 64 + g * 16, ar);
    int br = 1 + cb + 16 * i + r;
    sb[i] = AREG + SWZ(br * 64 + g * 16, br);
  }
  f32x4 acc[2][2];
  #pragma unroll
  for (int ai = 0; ai < 2; ++ai)
    #pragma unroll
    for (int bj = 0; bj < 2; ++bj) acc[ai][bj] = (f32x4){0.f, 0.f, 0.f, 0.f};

  int piu = 0;
  for (int it = 0; it < 16; ++it){
    __syncthreads();                         // prev-iter reads (or zero-init) done
    if (it){                                 // rezero exactly the 4 slots we wrote
      #pragma unroll
      for (int a = 0; a < 4; ++a){
        int row = piu + a;
        *(unsigned short*)(lds + SWZ(sbase + row * 64, row)) = 0;
      }
    }
    const float val = gsrc[gbase + (size_t)it * 128];
    {
      float u = (val - mn) * sc;
      float fu = floorf(u); int iu = (int)fu; float f = u - fu, q = 1.f - f;
      float w0 = q*q*q*(1.f/6.f), w3 = f*f*f*(1.f/6.f);
      float w1 = (2.f/3.f) - f*f + 0.5f*f*f*f, w2 = 1.f - w0 - w1 - w3;
      float w[4] = {w0, w1, w2, w3};
      piu = iu;
      #pragma unroll
      for (int a = 0; a < 4; ++a){
        int row = iu + a;                    // lds row = bin+1
        *(unsigned short*)(lds + SWZ(sbase + row * 64, row)) = f2bf(w[a]);
      }
    }
    __syncthreads();                         // all columns scattered
    #pragma unroll
    for (int kb = 0; kb < KBLK; ++kb){
      const char* p = lds + kb * TILEB;
      bf16x8 a0 = *(const bf16x8*)(p + sa[0]);
      bf16x8 a1 = *(const bf16x8*)(p + sa[1]);
      bf16x8 b0 = *(const bf16x8*)(p + sb[0]);
      bf16x8 b1 = *(const bf16x8*)(p + sb[1]);
      acc[0][0] = __builtin_amdgcn_mfma_f32_16x16x32_bf16(a0, b0, acc[0][0], 0, 0, 0);
      acc[0][1] = __builtin_amdgcn_mfma_f32_16x16x32_bf16(a0, b1, acc[0][1], 0, 0, 0);
      acc[1][0] = __builtin_amdgcn_mfma_f32_16x16x32_bf16(a1, b0, acc[1][0], 0, 0, 0);
      acc[1][1] = __builtin_amdgcn_mfma_f32_16x16x32_bf16(a1, b1, acc[1][1], 0, 0, 0);
    }
  }
  // epilogue: atomicAdd wave's quadrant into hist[n].
  // C/D map col=lane&15 (r), row=(lane>>4)*4+e (m89-verified); 64 distinct
  // addresses per wave-instruction -> no intra-wave same-address contention.
  float* h = hist + n * 4096;
  #pragma unroll
  for (int ai = 0; ai < 2; ++ai)
    #pragma unroll
    for (int bj = 0; bj < 2; ++bj)
      #pragma unroll
      for (int e = 0; e < 4; ++e)
        atomicAdd(&h[(rb + 16 * ai + g * 4 + e) * 64 + cb + 16 * bj + r],
                  acc[ai][bj][e]);
  __threadfence();
  if (tid == 0) fl = atomicAdd(&cnt[n], 1);
  __syncthreads();
  if (fl != WPS - 1) return;                 // not the last block of sample n
  __threadfence();

  // ---- entropy tail for sample n (one block) ----
  if (tid < NB){ rowsum[tid] = 0.f; colsum[tid] = 0.f; }
  __syncthreads();
  const int rr = tid >> 2, c0 = (tid & 3) * 16;
  float hv[16];
  float rsum = 0.f;
  #pragma unroll
  for (int k = 0; k < 16; ++k){
    hv[k] = atomicAdd(&h[rr * 64 + c0 + k], 0.f);   // coherent read
    rsum += hv[k];
  }
  atomicAdd(&rowsum[rr], rsum);
  #pragma unroll
  for (int k = 0; k < 16; ++k) atomicAdd(&colsum[c0 + k], hv[k]);
  float part = rsum;
  for (int off = 32; off; off >>= 1) part += __shfl_down(part, off);
  if ((tid & 63) == 0) wr1[tid >> 6] = part;
  __syncthreads();
  if (tid == 0) S_sh = wr1[0] + wr1[1] + wr1[2] + wr1[3];
  __syncthreads();
  const float invS = 1.f / S_sh;
  float ej = 0.f;
  #pragma unroll
  for (int k = 0; k < 16; ++k){
    float p = hv[k] * invS;
    ej -= p * logf(p + 1e-12f);
  }
  for (int off = 32; off; off >>= 1) ej += __shfl_down(ej, off);
  if ((tid & 63) == 0) wr2[tid >> 6] = ej;
  float em = 0.f;
  if (tid < NB){
    float pt = rowsum[tid] * invS;
    float ps = colsum[tid] * invS;
    em = -pt * logf(pt + 1e-12f) - ps * logf(ps + 1e-12f);
    for (int off = 32; off; off >>= 1) em += __shfl_down(em, off);
  }
  __syncthreads();
  if (tid == 0){
    float EJ = wr2[0] + wr2[1] + wr2[2] + wr2[3];
    atomicExch(&ratio[n], em / EJ);          // device-scope store
    __threadfence();
    int f2 = atomicAdd(&cnt[4], 1);
    if (f2 == NSAMP - 1){                    // last sample finisher
      __threadfence();
      float s = 0.f;
      #pragma unroll
      for (int m = 0; m < NSAMP; ++m) s += atomicAdd(&ratio[m], 0.f);
      out[0] = -0.25f * s;
    }
  }
}

extern "C" void kernel_launch(void* const* d_in, const int* in_sizes, int n_in,
                              void* d_out, int out_size, void* d_ws, size_t ws_size,
                              hipStream_t stream){
  const float* tgt = (const float*)d_in[0];
  const float* src = (const float*)d_in[1];
  float* out = (float*)d_out;
  char* ws = (char*)d_ws;
  // ws: [0,8K) mmp 512*float4 | [8K,+32) cnt | [8320,+16) ratio | [8448,+64K) hist
  float4* mmp = (float4*)ws;
  int*   cnt  = (int*)(ws + 8192);
  float* ratio= (float*)(ws + 8320);
  float* hist = (float*)(ws + 8448);
  k_minmax<<<NSAMP * 128, 256, 0, stream>>>(tgt, src, mmp, hist, cnt);
  k_hist  <<<NSAMP * WPS, 256, 0, stream>>>(tgt, src, mmp, hist, ratio, cnt, out);
}